// Round 17
// baseline (1194.705 us; speedup 1.0000x reference)
//
#include <hip/hip_runtime.h>
#include <math.h>

#define Bsz    2048
#define Ccnt   100000
#define Dd     128
#define CT     128                 // classes per margin block
#define NMBLK  782                 // ceil(Ccnt/CT)
#define NCHUNK (Bsz / 32)          // 64 sample chunks of 32
#define MFIRST 800                 // margin block slots at the FRONT of the grid
#define SBLKS  2400                // scale blocks
#define GRID_G (MFIRST + SBLKS)
#define N4     (Bsz * (Ccnt / 4))  // 51.2M float4 elements; N4 % 8 == 0

typedef short  bf16x8  __attribute__((ext_vector_type(8)));
typedef float  f32x16  __attribute__((ext_vector_type(16)));
typedef float  f32x4   __attribute__((ext_vector_type(4)));

// ---- order-preserving float <-> uint encoding for atomicMax ----
static __device__ __forceinline__ unsigned int enc_f32(float f) {
    unsigned int u = __float_as_uint(f);
    return (u & 0x80000000u) ? ~u : (u | 0x80000000u);
}
static __device__ __forceinline__ float dec_f32(unsigned int u) {
    unsigned int b = (u & 0x80000000u) ? (u & 0x7fffffffu) : ~u;
    return __uint_as_float(b);
}
// fp32 -> bf16 round-to-nearest-even
static __device__ __forceinline__ unsigned short f2bf(float f) {
    unsigned int u = __float_as_uint(f);
    unsigned int r = ((u >> 16) & 1u) + 0x7fffu;
    return (unsigned short)((u + r) >> 16);
}

// ---- prep: pack Q = wnorm[labels] as bf16 in MFMA B-fragment order.
// Fragment (p,t), lane l: Q[s = p*32+(l&31)][d = (l>>5)*8 + t*16 .. +8].
__global__ __launch_bounds__(256) void prep_kernel(
    const int* __restrict__ labels,
    const float* __restrict__ wnorm,
    bf16x8* __restrict__ qpk,
    unsigned int* __restrict__ maxbuf)
{
    int tid = blockIdx.x * 256 + threadIdx.x;   // 32768 threads
    if (tid < Bsz) maxbuf[tid] = 0u;            // reset running-max (enc space)
    int b   = tid >> 4;                         // sample
    int c8  = (tid & 15) << 3;                  // first of this thread's 8 dims
    if (b >= Bsz) return;
    int lab = labels[b];
    if (lab < 0) lab = 0;
    const float* src = wnorm + (size_t)lab * Dd + c8;
    float4 u = *reinterpret_cast<const float4*>(src);
    float4 v = *reinterpret_cast<const float4*>(src + 4);
    unsigned short o[8] = { f2bf(u.x), f2bf(u.y), f2bf(u.z), f2bf(u.w),
                            f2bf(v.x), f2bf(v.y), f2bf(v.z), f2bf(v.w) };
    int p = b >> 5, t = c8 >> 4, l = ((c8 >> 3) & 1) * 32 + (b & 31);
    qpk[(size_t)(p * 8 + t) * 64 + l] = *reinterpret_cast<bf16x8*>(o);
}

// ---- margin role, slimmed for <=128 VGPR (4 blocks/CU with scale):
// direct loads (TLP covers L2 latency), single acc chain, 4-temp max.
template<bool EDGE>
__device__ __forceinline__ void margin_chunks(
    const int* __restrict__ labels,
    const bf16x8* __restrict__ qpk,
    const bf16x8 (&afr)[8], int base_c, int lane,
    unsigned int* smax)
{
    const int lm  = lane & 31;
    const int lim = Ccnt - base_c;   // only used when EDGE

    for (int ch = 0; ch < NCHUNK; ++ch) {
        const int s = ch * 32 + lm;
        const bf16x8* qw = qpk + (size_t)ch * 512;
        bf16x8 b0 = qw[0 * 64 + lane], b1 = qw[1 * 64 + lane];
        bf16x8 b2 = qw[2 * 64 + lane], b3 = qw[3 * 64 + lane];
        bf16x8 b4 = qw[4 * 64 + lane], b5 = qw[5 * 64 + lane];
        bf16x8 b6 = qw[6 * 64 + lane], b7 = qw[7 * 64 + lane];

        f32x16 acc = {};
        acc = __builtin_amdgcn_mfma_f32_32x32x16_bf16(afr[0], b0, acc, 0, 0, 0);
        acc = __builtin_amdgcn_mfma_f32_32x32x16_bf16(afr[1], b1, acc, 0, 0, 0);
        acc = __builtin_amdgcn_mfma_f32_32x32x16_bf16(afr[2], b2, acc, 0, 0, 0);
        acc = __builtin_amdgcn_mfma_f32_32x32x16_bf16(afr[3], b3, acc, 0, 0, 0);
        acc = __builtin_amdgcn_mfma_f32_32x32x16_bf16(afr[4], b4, acc, 0, 0, 0);
        acc = __builtin_amdgcn_mfma_f32_32x32x16_bf16(afr[5], b5, acc, 0, 0, 0);
        acc = __builtin_amdgcn_mfma_f32_32x32x16_bf16(afr[6], b6, acc, 0, 0, 0);
        acc = __builtin_amdgcn_mfma_f32_32x32x16_bf16(afr[7], b7, acc, 0, 0, 0);

        const int rel = labels[s] - base_c;

        float mm0 = -3.0f, mm1 = -3.0f, mm2 = -3.0f, mm3 = -3.0f;
#pragma unroll
        for (int r = 0; r < 16; ++r) {
            const int row = (r & 3) + 8 * (r >> 2);
            float tv = acc[r];
            bool kill = (rel == row);
            if (EDGE) kill = kill || (row >= lim);
            tv = kill ? -3.0f : tv;
            if ((r & 3) == 0) mm0 = fmaxf(mm0, tv);
            if ((r & 3) == 1) mm1 = fmaxf(mm1, tv);
            if ((r & 3) == 2) mm2 = fmaxf(mm2, tv);
            if ((r & 3) == 3) mm3 = fmaxf(mm3, tv);
        }
        float m = fmaxf(fmaxf(mm0, mm1), fmaxf(mm2, mm3));
        m = fmaxf(m, __shfl_xor(m, 32));    // join the two K-half lane sets
        if (lane < 32) atomicMax(&smax[s], enc_f32(m));
    }
}

__device__ __forceinline__ void margin_body(
    int mb,
    const int* __restrict__ labels,
    const float* __restrict__ wnorm,
    const bf16x8* __restrict__ qpk,
    unsigned int* __restrict__ maxbuf)
{
    __shared__ unsigned int smax[Bsz];
    for (int i = threadIdx.x; i < Bsz; i += 256) smax[i] = 0u;
    __syncthreads();

    const int wave  = threadIdx.x >> 6;
    const int lane  = threadIdx.x & 63;
    const int h     = lane >> 5;
    const int lm    = lane & 31;
    const int cbase = mb * CT + wave * 32;
    const int cls   = cbase + lm;
    const bool cvalid = cls < Ccnt;

    bf16x8 afr[8];
    {
        const float* wr = wnorm + (size_t)(cvalid ? cls : 0) * Dd + h * 8;
#pragma unroll
        for (int t = 0; t < 8; ++t) {
            float4 u = *reinterpret_cast<const float4*>(wr + t * 16);
            float4 v = *reinterpret_cast<const float4*>(wr + t * 16 + 4);
            if (!cvalid) { u = make_float4(0,0,0,0); v = make_float4(0,0,0,0); }
            unsigned short o[8] = { f2bf(u.x), f2bf(u.y), f2bf(u.z), f2bf(u.w),
                                    f2bf(v.x), f2bf(v.y), f2bf(v.z), f2bf(v.w) };
            afr[t] = *reinterpret_cast<bf16x8*>(o);
        }
    }
    const int base_c = cbase + 4 * h;

    if (mb == NMBLK - 1)
        margin_chunks<true >(labels, qpk, afr, base_c, lane, smax);
    else
        margin_chunks<false>(labels, qpk, afr, base_c, lane, smax);

    __syncthreads();
    for (int i = threadIdx.x; i < Bsz; i += 256)
        atomicMax(&maxbuf[i], smax[i]);
}

// ---- scale role: out = logits * 64, nontemporal x8 float4.
// 8 loads issued back-to-back = 32KB outstanding per block: even 224
// resident scale blocks hold 7.3MB >= the ~5.7MB bandwidth-delay product,
// so HBM stays saturated while margin occupies the other slots. (x2 unroll
// held only 8KB/block -> HBM sagged whenever margin coexisted; that was
// the schedule-invariant ~100us overhead of rounds 12-16.)
__device__ __forceinline__ void scale_body(
    int sidx, const f32x4* __restrict__ in, f32x4* __restrict__ out)
{
    const int stride = SBLKS * 256 * 8;
    for (int i = (sidx * 256 + (int)threadIdx.x) * 8; i < N4; i += stride) {
        f32x4 v0 = __builtin_nontemporal_load(in + i);
        f32x4 v1 = __builtin_nontemporal_load(in + i + 1);
        f32x4 v2 = __builtin_nontemporal_load(in + i + 2);
        f32x4 v3 = __builtin_nontemporal_load(in + i + 3);
        f32x4 v4 = __builtin_nontemporal_load(in + i + 4);
        f32x4 v5 = __builtin_nontemporal_load(in + i + 5);
        f32x4 v6 = __builtin_nontemporal_load(in + i + 6);
        f32x4 v7 = __builtin_nontemporal_load(in + i + 7);
        v0 *= 64.f; v1 *= 64.f; v2 *= 64.f; v3 *= 64.f;
        v4 *= 64.f; v5 *= 64.f; v6 *= 64.f; v7 *= 64.f;
        __builtin_nontemporal_store(v0, out + i);
        __builtin_nontemporal_store(v1, out + i + 1);
        __builtin_nontemporal_store(v2, out + i + 2);
        __builtin_nontemporal_store(v3, out + i + 3);
        __builtin_nontemporal_store(v4, out + i + 4);
        __builtin_nontemporal_store(v5, out + i + 5);
        __builtin_nontemporal_store(v6, out + i + 6);
        __builtin_nontemporal_store(v7, out + i + 7);
    }
}

// ---- fused kernel: all margin at the front (drains in first ~120us
// while deep-pipelined scale saturates HBM), then pure scale streaming.
__global__ __launch_bounds__(256, 4) void mega_kernel(
    const int* __restrict__ labels,
    const float* __restrict__ wnorm,
    const bf16x8* __restrict__ qpk,
    unsigned int* __restrict__ maxbuf,
    const f32x4* __restrict__ in,
    f32x4* __restrict__ out)
{
    const int bid = blockIdx.x;
    if (bid < MFIRST) {                       // margin block
        if (bid < NMBLK)
            margin_body(bid, labels, wnorm, qpk, maxbuf);
        // bids 782..799 idle (negligible)
    } else {                                  // scale block
        scale_body(bid - MFIRST, in, out);
    }
}

// ---- per-sample target fixup ----
__global__ void fixup_kernel(const float* __restrict__ logits,
                             const int* __restrict__ labels,
                             const unsigned int* __restrict__ maxbuf,
                             float* __restrict__ out)
{
    int b = blockIdx.x * blockDim.x + threadIdx.x;
    if (b >= Bsz) return;
    int lab = labels[b];
    if (lab < 0) return;
    float mx = dec_f32(maxbuf[b]);
    mx = fminf(fmaxf(mx, -1.f), 1.f);
    float theta  = acosf(mx);
    float d      = theta - 1.0f;                                 // K1
    float smooth = 0.012f / powf(1.0f + fabsf(d) * 20.0f, 1.1f); // 0.03*K3
    float margin = fmaxf(d, 0.f) * 0.1f + 0.4f + smooth;         // K2, K3
    size_t off = (size_t)b * Ccnt + lab;
    float x = logits[off];
    out[off] = cosf(acosf(x) + margin) * 64.0f;                  // S
}

extern "C" void kernel_launch(void* const* d_in, const int* in_sizes, int n_in,
                              void* d_out, int out_size, void* d_ws, size_t ws_size,
                              hipStream_t stream)
{
    const float* logits = (const float*)d_in[0];
    const int*   labels = (const int*)d_in[1];
    const float* wnorm  = (const float*)d_in[2];
    float* out = (float*)d_out;

    unsigned int* maxbuf = (unsigned int*)d_ws;                 // 8 KB
    bf16x8*       qpk    = (bf16x8*)((char*)d_ws + 8192);       // 512 KB

    prep_kernel<<<(Bsz * (Dd / 8) + 255) / 256, 256, 0, stream>>>(
        labels, wnorm, qpk, maxbuf);

    mega_kernel<<<GRID_G, 256, 0, stream>>>(
        labels, wnorm, qpk, maxbuf,
        (const f32x4*)logits, (f32x4*)out);

    fixup_kernel<<<(Bsz + 255) / 256, 256, 0, stream>>>(
        logits, labels, maxbuf, out);
}

// Round 18
// 321.158 us; speedup vs baseline: 3.7200x; 3.7200x over previous
//
#include <hip/hip_runtime.h>
#include <math.h>

#define Bsz    2048
#define Ccnt   100000
#define Dd     128
#define CT     128                 // classes per margin block
#define NMBLK  782                 // ceil(Ccnt/CT)
#define NCHUNK (Bsz / 32)          // 64 sample chunks of 32
#define MFIRST 800                 // margin block slots at the FRONT of the grid
#define SBLKS  2400                // scale blocks
#define GRID_G (MFIRST + SBLKS)
#define N4     (Bsz * (Ccnt / 4))  // 51.2M float4; N4 = 25000 * 2048 (tail-free)

typedef short  bf16x8  __attribute__((ext_vector_type(8)));
typedef float  f32x16  __attribute__((ext_vector_type(16)));
typedef float  f32x4   __attribute__((ext_vector_type(4)));

// ---- order-preserving float <-> uint encoding for atomicMax ----
static __device__ __forceinline__ unsigned int enc_f32(float f) {
    unsigned int u = __float_as_uint(f);
    return (u & 0x80000000u) ? ~u : (u | 0x80000000u);
}
static __device__ __forceinline__ float dec_f32(unsigned int u) {
    unsigned int b = (u & 0x80000000u) ? (u & 0x7fffffffu) : ~u;
    return __uint_as_float(b);
}
// fp32 -> bf16 round-to-nearest-even
static __device__ __forceinline__ unsigned short f2bf(float f) {
    unsigned int u = __float_as_uint(f);
    unsigned int r = ((u >> 16) & 1u) + 0x7fffu;
    return (unsigned short)((u + r) >> 16);
}

// ---- prep: pack Q = wnorm[labels] as bf16 in MFMA B-fragment order.
// Fragment (p,t), lane l: Q[s = p*32+(l&31)][d = (l>>5)*8 + t*16 .. +8].
__global__ __launch_bounds__(256) void prep_kernel(
    const int* __restrict__ labels,
    const float* __restrict__ wnorm,
    bf16x8* __restrict__ qpk,
    unsigned int* __restrict__ maxbuf)
{
    int tid = blockIdx.x * 256 + threadIdx.x;   // 32768 threads
    if (tid < Bsz) maxbuf[tid] = 0u;            // reset running-max (enc space)
    int b   = tid >> 4;                         // sample
    int c8  = (tid & 15) << 3;                  // first of this thread's 8 dims
    if (b >= Bsz) return;
    int lab = labels[b];
    if (lab < 0) lab = 0;
    const float* src = wnorm + (size_t)lab * Dd + c8;
    float4 u = *reinterpret_cast<const float4*>(src);
    float4 v = *reinterpret_cast<const float4*>(src + 4);
    unsigned short o[8] = { f2bf(u.x), f2bf(u.y), f2bf(u.z), f2bf(u.w),
                            f2bf(v.x), f2bf(v.y), f2bf(v.z), f2bf(v.w) };
    int p = b >> 5, t = c8 >> 4, l = ((c8 >> 3) & 1) * 32 + (b & 31);
    qpk[(size_t)(p * 8 + t) * 64 + l] = *reinterpret_cast<bf16x8*>(o);
}

// ---- margin role, slimmed for <=128 VGPR (4 blocks/CU with scale):
// direct loads (TLP covers L2 latency), single acc chain, 4-temp max.
template<bool EDGE>
__device__ __forceinline__ void margin_chunks(
    const int* __restrict__ labels,
    const bf16x8* __restrict__ qpk,
    const bf16x8 (&afr)[8], int base_c, int lane,
    unsigned int* smax)
{
    const int lm  = lane & 31;
    const int lim = Ccnt - base_c;   // only used when EDGE

    for (int ch = 0; ch < NCHUNK; ++ch) {
        const int s = ch * 32 + lm;
        const bf16x8* qw = qpk + (size_t)ch * 512;
        bf16x8 b0 = qw[0 * 64 + lane], b1 = qw[1 * 64 + lane];
        bf16x8 b2 = qw[2 * 64 + lane], b3 = qw[3 * 64 + lane];
        bf16x8 b4 = qw[4 * 64 + lane], b5 = qw[5 * 64 + lane];
        bf16x8 b6 = qw[6 * 64 + lane], b7 = qw[7 * 64 + lane];

        f32x16 acc = {};
        acc = __builtin_amdgcn_mfma_f32_32x32x16_bf16(afr[0], b0, acc, 0, 0, 0);
        acc = __builtin_amdgcn_mfma_f32_32x32x16_bf16(afr[1], b1, acc, 0, 0, 0);
        acc = __builtin_amdgcn_mfma_f32_32x32x16_bf16(afr[2], b2, acc, 0, 0, 0);
        acc = __builtin_amdgcn_mfma_f32_32x32x16_bf16(afr[3], b3, acc, 0, 0, 0);
        acc = __builtin_amdgcn_mfma_f32_32x32x16_bf16(afr[4], b4, acc, 0, 0, 0);
        acc = __builtin_amdgcn_mfma_f32_32x32x16_bf16(afr[5], b5, acc, 0, 0, 0);
        acc = __builtin_amdgcn_mfma_f32_32x32x16_bf16(afr[6], b6, acc, 0, 0, 0);
        acc = __builtin_amdgcn_mfma_f32_32x32x16_bf16(afr[7], b7, acc, 0, 0, 0);

        const int rel = labels[s] - base_c;

        float mm0 = -3.0f, mm1 = -3.0f, mm2 = -3.0f, mm3 = -3.0f;
#pragma unroll
        for (int r = 0; r < 16; ++r) {
            const int row = (r & 3) + 8 * (r >> 2);
            float tv = acc[r];
            bool kill = (rel == row);
            if (EDGE) kill = kill || (row >= lim);
            tv = kill ? -3.0f : tv;
            if ((r & 3) == 0) mm0 = fmaxf(mm0, tv);
            if ((r & 3) == 1) mm1 = fmaxf(mm1, tv);
            if ((r & 3) == 2) mm2 = fmaxf(mm2, tv);
            if ((r & 3) == 3) mm3 = fmaxf(mm3, tv);
        }
        float m = fmaxf(fmaxf(mm0, mm1), fmaxf(mm2, mm3));
        m = fmaxf(m, __shfl_xor(m, 32));    // join the two K-half lane sets
        if (lane < 32) atomicMax(&smax[s], enc_f32(m));
    }
}

__device__ __forceinline__ void margin_body(
    int mb,
    const int* __restrict__ labels,
    const float* __restrict__ wnorm,
    const bf16x8* __restrict__ qpk,
    unsigned int* __restrict__ maxbuf)
{
    __shared__ unsigned int smax[Bsz];
    for (int i = threadIdx.x; i < Bsz; i += 256) smax[i] = 0u;
    __syncthreads();

    const int wave  = threadIdx.x >> 6;
    const int lane  = threadIdx.x & 63;
    const int h     = lane >> 5;
    const int lm    = lane & 31;
    const int cbase = mb * CT + wave * 32;
    const int cls   = cbase + lm;
    const bool cvalid = cls < Ccnt;

    bf16x8 afr[8];
    {
        const float* wr = wnorm + (size_t)(cvalid ? cls : 0) * Dd + h * 8;
#pragma unroll
        for (int t = 0; t < 8; ++t) {
            float4 u = *reinterpret_cast<const float4*>(wr + t * 16);
            float4 v = *reinterpret_cast<const float4*>(wr + t * 16 + 4);
            if (!cvalid) { u = make_float4(0,0,0,0); v = make_float4(0,0,0,0); }
            unsigned short o[8] = { f2bf(u.x), f2bf(u.y), f2bf(u.z), f2bf(u.w),
                                    f2bf(v.x), f2bf(v.y), f2bf(v.z), f2bf(v.w) };
            afr[t] = *reinterpret_cast<bf16x8*>(o);
        }
    }
    const int base_c = cbase + 4 * h;

    if (mb == NMBLK - 1)
        margin_chunks<true >(labels, qpk, afr, base_c, lane, smax);
    else
        margin_chunks<false>(labels, qpk, afr, base_c, lane, smax);

    __syncthreads();
    for (int i = threadIdx.x; i < Bsz; i += 256)
        atomicMax(&maxbuf[i], smax[i]);
}

// ---- scale role: out = logits * 64, nontemporal x8 float4, INTERLEAVED.
// Per instruction, the 256 threads access 256 consecutive float4s (4KB
// contiguous, full-line NT stores); 8 such loads issued back-to-back give
// 32KB outstanding per block (BDP coverage) WITHOUT breaking coalescing.
// (Round 17 used thread-blocked i=tid*8+k: lanes 128B apart per instr ->
// partial-line NT stores -> WRITE_SIZE 1.9GB, 2.2TB/s. This fixes that.)
__device__ __forceinline__ void scale_body(
    int sidx, const f32x4* __restrict__ in, f32x4* __restrict__ out)
{
    const int stride = SBLKS * 2048;          // 2048 float4 per block-tile
    for (int i = sidx * 2048 + (int)threadIdx.x; i < N4; i += stride) {
        f32x4 v0 = __builtin_nontemporal_load(in + i);
        f32x4 v1 = __builtin_nontemporal_load(in + i + 256);
        f32x4 v2 = __builtin_nontemporal_load(in + i + 512);
        f32x4 v3 = __builtin_nontemporal_load(in + i + 768);
        f32x4 v4 = __builtin_nontemporal_load(in + i + 1024);
        f32x4 v5 = __builtin_nontemporal_load(in + i + 1280);
        f32x4 v6 = __builtin_nontemporal_load(in + i + 1536);
        f32x4 v7 = __builtin_nontemporal_load(in + i + 1792);
        v0 *= 64.f; v1 *= 64.f; v2 *= 64.f; v3 *= 64.f;
        v4 *= 64.f; v5 *= 64.f; v6 *= 64.f; v7 *= 64.f;
        __builtin_nontemporal_store(v0, out + i);
        __builtin_nontemporal_store(v1, out + i + 256);
        __builtin_nontemporal_store(v2, out + i + 512);
        __builtin_nontemporal_store(v3, out + i + 768);
        __builtin_nontemporal_store(v4, out + i + 1024);
        __builtin_nontemporal_store(v5, out + i + 1280);
        __builtin_nontemporal_store(v6, out + i + 1536);
        __builtin_nontemporal_store(v7, out + i + 1792);
    }
}

// ---- fused kernel: all margin at the front (drains in first ~120us
// while deep-pipelined scale saturates HBM), then pure scale streaming.
__global__ __launch_bounds__(256, 4) void mega_kernel(
    const int* __restrict__ labels,
    const float* __restrict__ wnorm,
    const bf16x8* __restrict__ qpk,
    unsigned int* __restrict__ maxbuf,
    const f32x4* __restrict__ in,
    f32x4* __restrict__ out)
{
    const int bid = blockIdx.x;
    if (bid < MFIRST) {                       // margin block
        if (bid < NMBLK)
            margin_body(bid, labels, wnorm, qpk, maxbuf);
        // bids 782..799 idle (negligible)
    } else {                                  // scale block
        scale_body(bid - MFIRST, in, out);
    }
}

// ---- per-sample target fixup ----
__global__ void fixup_kernel(const float* __restrict__ logits,
                             const int* __restrict__ labels,
                             const unsigned int* __restrict__ maxbuf,
                             float* __restrict__ out)
{
    int b = blockIdx.x * blockDim.x + threadIdx.x;
    if (b >= Bsz) return;
    int lab = labels[b];
    if (lab < 0) return;
    float mx = dec_f32(maxbuf[b]);
    mx = fminf(fmaxf(mx, -1.f), 1.f);
    float theta  = acosf(mx);
    float d      = theta - 1.0f;                                 // K1
    float smooth = 0.012f / powf(1.0f + fabsf(d) * 20.0f, 1.1f); // 0.03*K3
    float margin = fmaxf(d, 0.f) * 0.1f + 0.4f + smooth;         // K2, K3
    size_t off = (size_t)b * Ccnt + lab;
    float x = logits[off];
    out[off] = cosf(acosf(x) + margin) * 64.0f;                  // S
}

extern "C" void kernel_launch(void* const* d_in, const int* in_sizes, int n_in,
                              void* d_out, int out_size, void* d_ws, size_t ws_size,
                              hipStream_t stream)
{
    const float* logits = (const float*)d_in[0];
    const int*   labels = (const int*)d_in[1];
    const float* wnorm  = (const float*)d_in[2];
    float* out = (float*)d_out;

    unsigned int* maxbuf = (unsigned int*)d_ws;                 // 8 KB
    bf16x8*       qpk    = (bf16x8*)((char*)d_ws + 8192);       // 512 KB

    prep_kernel<<<(Bsz * (Dd / 8) + 255) / 256, 256, 0, stream>>>(
        labels, wnorm, qpk, maxbuf);

    mega_kernel<<<GRID_G, 256, 0, stream>>>(
        labels, wnorm, qpk, maxbuf,
        (const f32x4*)logits, (f32x4*)out);

    fixup_kernel<<<(Bsz + 255) / 256, 256, 0, stream>>>(
        logits, labels, maxbuf, out);
}